// Round 3
// baseline (322.650 us; speedup 1.0000x reference)
//
#include <hip/hip_runtime.h>

#define N_PTS 131072
#define C_DIM 128
#define NS_K  16
#define BN_EPS 1e-5f

typedef unsigned short ushort_t;
typedef unsigned short u16x8 __attribute__((ext_vector_type(8)));
typedef __bf16 bf16x8 __attribute__((ext_vector_type(8)));
typedef float f32x4 __attribute__((ext_vector_type(4)));

__device__ __forceinline__ ushort_t f2b(float f) {
    unsigned int u = __float_as_uint(f);
    u += 0x7FFFu + ((u >> 16) & 1u);          // round-to-nearest-even
    return (ushort_t)(u >> 16);
}
__device__ __forceinline__ float b2f(ushort_t h) {
    return __uint_as_float((unsigned int)h << 16);
}

// ---------------------------------------------------------------------------
// Prep: wT[n][k] = bf16(W[k][n]) for both weight matrices (one-shot, 64 KB).
// ---------------------------------------------------------------------------
__global__ __launch_bounds__(256) void prep_w_kernel(
    const float* __restrict__ W1, const float* __restrict__ W2,
    ushort_t* __restrict__ wT1, ushort_t* __restrict__ wT2)
{
    const int t = blockIdx.x * 256 + threadIdx.x;   // 0..16383
    const int n = t & 127;
    const int k = t >> 7;
    wT1[n * 128 + k] = f2b(W1[k * 128 + n]);
    wT2[n * 128 + k] = f2b(W2[k * 128 + n]);
}

// ---------------------------------------------------------------------------
// LDS-free MFMA GEMM: out_bf16[N,128] = A[N,128] @ W[128,128] + bias (+BN sums)
// 256 thr / 4 waves per block; block = 128 rows. Wave w: row-tiles {2w,2w+1},
// all 8 col-tiles. A frags loaded direct from global (16 B/lane), B frags from
// pre-transposed bf16 wT (L1/L2-broadcast across all blocks). No K-loop LDS,
// no barriers.
// Fragment layouts (validated round 2): A[m=lane&15][k=q*8+j];
// B[k=q*8+j][n=lane&15] from wT[n][k]; C/D col=lane&15, row=q*4+reg.
// ---------------------------------------------------------------------------
template <bool A_BF16, bool STATS>
__global__ __launch_bounds__(256) void gemm_mfma_kernel(
    const void* __restrict__ Aptr, const ushort_t* __restrict__ wT,
    const float* __restrict__ bias, ushort_t* __restrict__ out,
    float* __restrict__ gsum, float* __restrict__ gsq)
{
    __shared__ float s_sum[128];
    __shared__ float s_sq[128];

    const int tid  = threadIdx.x;
    const int lane = tid & 63;
    const int wv   = tid >> 6;
    const int m16  = lane & 15;
    const int q    = lane >> 4;
    const int base = blockIdx.x * 128;

    if (STATS) {
        if (tid < 128) { s_sum[tid] = 0.f; s_sq[tid] = 0.f; }
        __syncthreads();
    }

    const size_t row0 = (size_t)base + (wv * 2 + 0) * 16 + m16;
    const size_t row1 = (size_t)base + (wv * 2 + 1) * 16 + m16;

    f32x4 acc[2][8];
    #pragma unroll
    for (int i = 0; i < 2; i++)
        #pragma unroll
        for (int c = 0; c < 8; c++) acc[i][c] = (f32x4){0.f, 0.f, 0.f, 0.f};

    #pragma unroll
    for (int k0 = 0; k0 < 128; k0 += 32) {
        const int koff = q * 8 + k0;
        bf16x8 a0, a1;
        if (A_BF16) {
            const ushort_t* ab = (const ushort_t*)Aptr;
            a0 = __builtin_bit_cast(bf16x8, *(const u16x8*)(ab + row0 * 128 + koff));
            a1 = __builtin_bit_cast(bf16x8, *(const u16x8*)(ab + row1 * 128 + koff));
        } else {
            const float* af = (const float*)Aptr;
            const f32x4 l0 = *(const f32x4*)(af + row0 * 128 + koff);
            const f32x4 h0 = *(const f32x4*)(af + row0 * 128 + koff + 4);
            const f32x4 l1 = *(const f32x4*)(af + row1 * 128 + koff);
            const f32x4 h1 = *(const f32x4*)(af + row1 * 128 + koff + 4);
            u16x8 v0, v1;
            #pragma unroll
            for (int e = 0; e < 4; e++) {
                v0[e] = f2b(l0[e]); v0[4 + e] = f2b(h0[e]);
                v1[e] = f2b(l1[e]); v1[4 + e] = f2b(h1[e]);
            }
            a0 = __builtin_bit_cast(bf16x8, v0);
            a1 = __builtin_bit_cast(bf16x8, v1);
        }
        #pragma unroll
        for (int c = 0; c < 8; c++) {
            const bf16x8 b = __builtin_bit_cast(bf16x8,
                *(const u16x8*)(wT + (size_t)(c * 16 + m16) * 128 + koff));
            acc[0][c] = __builtin_amdgcn_mfma_f32_16x16x32_bf16(a0, b, acc[0][c], 0, 0, 0);
            acc[1][c] = __builtin_amdgcn_mfma_f32_16x16x32_bf16(a1, b, acc[1][c], 0, 0, 0);
        }
    }

    // ---- epilogue: bias, bf16 store, optional BN partial sums ----
    float psum[8], psq[8];
    #pragma unroll
    for (int c = 0; c < 8; c++) { psum[c] = 0.f; psq[c] = 0.f; }

    #pragma unroll
    for (int c = 0; c < 8; c++) {
        const int col = c * 16 + m16;
        const float bv = bias[col];
        #pragma unroll
        for (int i = 0; i < 2; i++) {
            const int rb = base + (wv * 2 + i) * 16 + q * 4;
            #pragma unroll
            for (int r = 0; r < 4; r++) {
                const float v = acc[i][c][r] + bv;
                out[(size_t)(rb + r) * 128 + col] = f2b(v);
                if (STATS) { psum[c] += v; psq[c] += v * v; }
            }
        }
    }

    if (STATS) {
        #pragma unroll
        for (int c = 0; c < 8; c++) {
            atomicAdd(&s_sum[c * 16 + m16], psum[c]);
            atomicAdd(&s_sq[c * 16 + m16],  psq[c]);
        }
        __syncthreads();
        if (tid < 128) {
            atomicAdd(&gsum[tid], s_sum[tid]);
            atomicAdd(&gsq[tid],  s_sq[tid]);
        }
    }
}

// ---------------------------------------------------------------------------
// Laplacian on bf16 table: lap[i,c] = mean_s relu(t[idx[i,s],c] - t[i,c])
// 16 points/block; 16 threads/point; 8 channels (16B) per thread.
// ---------------------------------------------------------------------------
__global__ __launch_bounds__(256) void laplacian_kernel(
    const ushort_t* __restrict__ table, const int* __restrict__ idx,
    ushort_t* __restrict__ lap)
{
    __shared__ int s_idx[256];
    const int tid = threadIdx.x;
    s_idx[tid] = idx[blockIdx.x * 256 + tid];
    __syncthreads();

    const int p  = tid >> 4;
    const int c8 = (tid & 15) * 8;
    const size_t pt = (size_t)blockIdx.x * 16 + p;

    const u16x8 cv = *(const u16x8*)(table + pt * 128 + c8);
    float ctr[8];
    #pragma unroll
    for (int e = 0; e < 8; e++) ctr[e] = b2f(cv[e]);

    float acc[8];
    #pragma unroll
    for (int e = 0; e < 8; e++) acc[e] = 0.f;

    #pragma unroll
    for (int s = 0; s < NS_K; s++) {
        const int j = s_idx[p * 16 + s];
        const u16x8 nv = *(const u16x8*)(table + (size_t)j * 128 + c8);
        #pragma unroll
        for (int e = 0; e < 8; e++)
            acc[e] += fmaxf(b2f(nv[e]) - ctr[e], 0.f);
    }

    u16x8 o;
    #pragma unroll
    for (int e = 0; e < 8; e++) o[e] = f2b(acc[e] * (1.f / (float)NS_K));
    *(u16x8*)(lap + pt * 128 + c8) = o;
}

// ---------------------------------------------------------------------------
// Fold BN stats into per-channel scale/shift (1 block, 128 threads).
// ---------------------------------------------------------------------------
__global__ void bn_stats_kernel(const float* __restrict__ gsum,
                                const float* __restrict__ gsq,
                                const float* __restrict__ gamma,
                                const float* __restrict__ beta,
                                float* __restrict__ bnsc, float* __restrict__ bnsh)
{
    const int c = threadIdx.x;
    const float invN = 1.f / (float)N_PTS;
    const float mean = gsum[c] * invN;
    const float var  = gsq[c] * invN - mean * mean;
    const float sc   = rsqrtf(var + BN_EPS) * gamma[c];
    bnsc[c] = sc;
    bnsh[c] = fmaf(-mean, sc, beta[c]);
}

// ---------------------------------------------------------------------------
// BN apply + ReLU: 8 elems (one bf16x8 load, two float4 stores) per thread.
// ---------------------------------------------------------------------------
__global__ __launch_bounds__(256) void bn_relu_kernel(
    const ushort_t* __restrict__ h, const float* __restrict__ bnsc,
    const float* __restrict__ bnsh, float* __restrict__ out)
{
    const size_t i = (size_t)blockIdx.x * 256 + threadIdx.x;
    const int c8 = (threadIdx.x * 8) & 127;   // block covers 2048 elems = 16 full rows

    const u16x8 hv = *(const u16x8*)(h + i * 8);
    const f32x4 sc0 = *(const f32x4*)(bnsc + c8);
    const f32x4 sc1 = *(const f32x4*)(bnsc + c8 + 4);
    const f32x4 sh0 = *(const f32x4*)(bnsh + c8);
    const f32x4 sh1 = *(const f32x4*)(bnsh + c8 + 4);

    f32x4 o0, o1;
    #pragma unroll
    for (int e = 0; e < 4; e++) {
        o0[e] = fmaxf(fmaf(b2f(hv[e]),     sc0[e], sh0[e]), 0.f);
        o1[e] = fmaxf(fmaf(b2f(hv[4 + e]), sc1[e], sh1[e]), 0.f);
    }
    float* op = out + (size_t)3 * N_PTS + i * 8;
    *(f32x4*)(op)     = o0;
    *(f32x4*)(op + 4) = o1;
}

// ---------------------------------------------------------------------------
// Copy p (N*3 floats) and write o (as float value in f32 out buffer).
// ---------------------------------------------------------------------------
__global__ __launch_bounds__(256) void copy_p_kernel(
    const float* __restrict__ p, const int* __restrict__ o,
    float* __restrict__ out)
{
    const size_t i = (size_t)blockIdx.x * 256 + threadIdx.x;
    *(f32x4*)(out + i * 4) = *(const f32x4*)(p + i * 4);
    if (i == 0)
        out[(size_t)3 * N_PTS + (size_t)N_PTS * C_DIM] = (float)o[0];
}

extern "C" void kernel_launch(void* const* d_in, const int* in_sizes, int n_in,
                              void* d_out, int out_size, void* d_ws, size_t ws_size,
                              hipStream_t stream) {
    const float* p     = (const float*)d_in[0];
    const float* u     = (const float*)d_in[1];
    const int*   o     = (const int*)d_in[2];
    const int*   idx   = (const int*)d_in[3];
    const float* W1    = (const float*)d_in[4];
    const float* b1    = (const float*)d_in[5];
    const float* W2    = (const float*)d_in[6];
    const float* b2    = (const float*)d_in[7];
    const float* gamma = (const float*)d_in[8];
    const float* beta  = (const float*)d_in[9];
    float* out = (float*)d_out;

    char* ws = (char*)d_ws;
    const size_t buf_bytes = (size_t)N_PTS * C_DIM * sizeof(ushort_t);  // 32 MB
    ushort_t* table = (ushort_t*)ws;                       // u_pre, bf16
    ushort_t* lap   = (ushort_t*)(ws + buf_bytes);         // laplacian, bf16
    ushort_t* h     = (ushort_t*)(ws + 2 * buf_bytes);     // pre-BN, bf16
    float*    stats = (float*)(ws + 3 * buf_bytes);
    float* gsum = stats;        // [128]
    float* gsq  = stats + 128;  // [128]
    float* bnsc = stats + 256;  // [128]
    float* bnsh = stats + 384;  // [128]
    ushort_t* wT1 = (ushort_t*)(stats + 512);              // [128*128] bf16
    ushort_t* wT2 = wT1 + 128 * 128;

    hipMemsetAsync(stats, 0, 256 * sizeof(float), stream);

    prep_w_kernel<<<64, 256, 0, stream>>>(W1, W2, wT1, wT2);
    gemm_mfma_kernel<false, false><<<N_PTS / 128, 256, 0, stream>>>(
        u, wT1, b1, table, nullptr, nullptr);
    laplacian_kernel<<<N_PTS / 16, 256, 0, stream>>>(table, idx, lap);
    gemm_mfma_kernel<true, true><<<N_PTS / 128, 256, 0, stream>>>(
        lap, wT2, b2, h, gsum, gsq);
    bn_stats_kernel<<<1, 128, 0, stream>>>(gsum, gsq, gamma, beta, bnsc, bnsh);
    bn_relu_kernel<<<(N_PTS * C_DIM / 8) / 256, 256, 0, stream>>>(
        h, bnsc, bnsh, out);
    copy_p_kernel<<<(3 * N_PTS / 4) / 256, 256, 0, stream>>>(p, o, out);
}

// Round 4
// 288.277 us; speedup vs baseline: 1.1192x; 1.1192x over previous
//
#include <hip/hip_runtime.h>

#define N_PTS 131072
#define C_DIM 128
#define NS_K  16
#define BN_EPS 1e-5f

typedef unsigned short ushort_t;
typedef unsigned short u16x8 __attribute__((ext_vector_type(8)));
typedef __bf16 bf16x8 __attribute__((ext_vector_type(8)));
typedef float f32x4 __attribute__((ext_vector_type(4)));

__device__ __forceinline__ ushort_t f2b(float f) {
    unsigned int u = __float_as_uint(f);
    u += 0x7FFFu + ((u >> 16) & 1u);          // round-to-nearest-even
    return (ushort_t)(u >> 16);
}
__device__ __forceinline__ float b2f(ushort_t h) {
    return __uint_as_float((unsigned int)h << 16);
}

// ---------------------------------------------------------------------------
// Prep: wT[n][k] = bf16(W[k][n]) for both weight matrices (one-shot, 64 KB).
// ---------------------------------------------------------------------------
__global__ __launch_bounds__(256) void prep_w_kernel(
    const float* __restrict__ W1, const float* __restrict__ W2,
    ushort_t* __restrict__ wT1, ushort_t* __restrict__ wT2)
{
    const int t = blockIdx.x * 256 + threadIdx.x;   // 0..16383
    const int n = t & 127;
    const int k = t >> 7;
    wT1[n * 128 + k] = f2b(W1[k * 128 + n]);
    wT2[n * 128 + k] = f2b(W2[k * 128 + n]);
}

// ---------------------------------------------------------------------------
// MFMA GEMM: out_bf16[N,128] = A[N,128] @ W[128,128] + bias (+ BN sums)
// 256 thr / 4 waves; block = 128 rows; K=128 LDS-resident (pitch 136 bf16).
// Wave w: row-tiles {2w,2w+1}, all 8 col-tiles; mfma_f32_16x16x32_bf16.
// Epilogue: C repacked via LDS -> fully-coalesced 16B stores (1 KB / wave-instr).
// Fragment layouts (validated rounds 2/3): A[m=lane&15][k=q*8+j];
// B[k=q*8+j][n=lane&15] from wT[n][k]; C/D col=lane&15, row=q*4+reg.
// ---------------------------------------------------------------------------
template <bool A_BF16, bool STATS>
__global__ __launch_bounds__(256) void gemm_mfma_kernel(
    const void* __restrict__ Aptr, const ushort_t* __restrict__ wT,
    const float* __restrict__ bias, ushort_t* __restrict__ out,
    float* __restrict__ gsum, float* __restrict__ gsq)
{
    __shared__ __align__(16) ushort_t a_sh[128 * 136];   // A tile, then C tile
    __shared__ __align__(16) ushort_t w_sh[128 * 136];   // wT tile [n][k]
    __shared__ float s_sum[128];
    __shared__ float s_sq[128];

    const int tid  = threadIdx.x;
    const int lane = tid & 63;
    const int wv   = tid >> 6;
    const int m16  = lane & 15;
    const int q    = lane >> 4;
    const int base = blockIdx.x * 128;

    if (STATS && tid < 128) { s_sum[tid] = 0.f; s_sq[tid] = 0.f; }

    // ---- stage A tile (128x128, convert f32->bf16 if needed) ----
    {
        const int row  = tid >> 1;
        const int half = (tid & 1) * 64;
        ushort_t* as = a_sh + row * 136 + half;
        if (A_BF16) {
            const ushort_t* ag = (const ushort_t*)Aptr + (size_t)(base + row) * 128 + half;
            #pragma unroll
            for (int j = 0; j < 8; j++)
                *(u16x8*)(as + j * 8) = *(const u16x8*)(ag + j * 8);
        } else {
            const float* ag = (const float*)Aptr + (size_t)(base + row) * 128 + half;
            #pragma unroll
            for (int j = 0; j < 8; j++) {
                f32x4 lo = *(const f32x4*)(ag + j * 8);
                f32x4 hi = *(const f32x4*)(ag + j * 8 + 4);
                u16x8 v;
                v[0] = f2b(lo[0]); v[1] = f2b(lo[1]); v[2] = f2b(lo[2]); v[3] = f2b(lo[3]);
                v[4] = f2b(hi[0]); v[5] = f2b(hi[1]); v[6] = f2b(hi[2]); v[7] = f2b(hi[3]);
                *(u16x8*)(as + j * 8) = v;
            }
        }
    }
    // ---- stage wT tile (bf16, already transposed; vector copy) ----
    {
        const int n    = tid >> 1;
        const int half = (tid & 1) * 64;
        const ushort_t* wg = wT + (size_t)n * 128 + half;
        ushort_t* ws = w_sh + n * 136 + half;
        #pragma unroll
        for (int j = 0; j < 8; j++)
            *(u16x8*)(ws + j * 8) = *(const u16x8*)(wg + j * 8);
    }
    __syncthreads();

    f32x4 acc[2][8];
    #pragma unroll
    for (int i = 0; i < 2; i++)
        #pragma unroll
        for (int c = 0; c < 8; c++) acc[i][c] = (f32x4){0.f, 0.f, 0.f, 0.f};

    const ushort_t* ap0 = a_sh + ((wv * 2 + 0) * 16 + m16) * 136 + q * 8;
    const ushort_t* ap1 = a_sh + ((wv * 2 + 1) * 16 + m16) * 136 + q * 8;
    const ushort_t* wp  = w_sh + m16 * 136 + q * 8;

    #pragma unroll
    for (int k0 = 0; k0 < 128; k0 += 32) {
        bf16x8 a0 = __builtin_bit_cast(bf16x8, *(const u16x8*)(ap0 + k0));
        bf16x8 a1 = __builtin_bit_cast(bf16x8, *(const u16x8*)(ap1 + k0));
        #pragma unroll
        for (int c = 0; c < 8; c++) {
            bf16x8 b = __builtin_bit_cast(bf16x8, *(const u16x8*)(wp + c * (16 * 136) + k0));
            acc[0][c] = __builtin_amdgcn_mfma_f32_16x16x32_bf16(a0, b, acc[0][c], 0, 0, 0);
            acc[1][c] = __builtin_amdgcn_mfma_f32_16x16x32_bf16(a1, b, acc[1][c], 0, 0, 0);
        }
    }

    __syncthreads();   // all MFMA LDS reads done; a_sh now reusable as C tile

    // ---- epilogue: bias, bf16 -> LDS C tile, BN partial sums ----
    float psum[8], psq[8];
    #pragma unroll
    for (int c = 0; c < 8; c++) { psum[c] = 0.f; psq[c] = 0.f; }

    #pragma unroll
    for (int c = 0; c < 8; c++) {
        const int col = c * 16 + m16;
        const float bv = bias[col];
        #pragma unroll
        for (int i = 0; i < 2; i++) {
            const int rb = (wv * 2 + i) * 16 + q * 4;
            #pragma unroll
            for (int r = 0; r < 4; r++) {
                const float v = acc[i][c][r] + bv;
                a_sh[(rb + r) * 136 + col] = f2b(v);
                if (STATS) { psum[c] += v; psq[c] += v * v; }
            }
        }
    }
    if (STATS) {
        #pragma unroll
        for (int c = 0; c < 8; c++) {
            atomicAdd(&s_sum[c * 16 + m16], psum[c]);
            atomicAdd(&s_sq[c * 16 + m16],  psq[c]);
        }
    }
    __syncthreads();

    // ---- coalesced write-out: 16 lanes cover one 256 B row ----
    {
        const int r0 = tid >> 4;            // 0..15
        const int c0 = (tid & 15) * 8;      // 16 B chunk within row
        #pragma unroll
        for (int it = 0; it < 8; it++) {
            const int rl = r0 + it * 16;
            const u16x8 v = *(const u16x8*)(a_sh + rl * 136 + c0);
            *(u16x8*)(out + (size_t)(base + rl) * 128 + c0) = v;
        }
    }
    if (STATS && tid < 128) {
        atomicAdd(&gsum[tid], s_sum[tid]);
        atomicAdd(&gsq[tid],  s_sq[tid]);
    }
}

// ---------------------------------------------------------------------------
// Laplacian on bf16 table: lap[i,c] = mean_s relu(t[idx[i,s],c] - t[i,c])
// 16 points/block; 16 threads/point; 8 channels (16B) per thread.
// ---------------------------------------------------------------------------
__global__ __launch_bounds__(256) void laplacian_kernel(
    const ushort_t* __restrict__ table, const int* __restrict__ idx,
    ushort_t* __restrict__ lap)
{
    __shared__ int s_idx[256];
    const int tid = threadIdx.x;
    s_idx[tid] = idx[blockIdx.x * 256 + tid];
    __syncthreads();

    const int p  = tid >> 4;
    const int c8 = (tid & 15) * 8;
    const size_t pt = (size_t)blockIdx.x * 16 + p;

    const u16x8 cv = *(const u16x8*)(table + pt * 128 + c8);
    float ctr[8];
    #pragma unroll
    for (int e = 0; e < 8; e++) ctr[e] = b2f(cv[e]);

    float acc[8];
    #pragma unroll
    for (int e = 0; e < 8; e++) acc[e] = 0.f;

    #pragma unroll
    for (int s = 0; s < NS_K; s++) {
        const int j = s_idx[p * 16 + s];
        const u16x8 nv = *(const u16x8*)(table + (size_t)j * 128 + c8);
        #pragma unroll
        for (int e = 0; e < 8; e++)
            acc[e] += fmaxf(b2f(nv[e]) - ctr[e], 0.f);
    }

    u16x8 o;
    #pragma unroll
    for (int e = 0; e < 8; e++) o[e] = f2b(acc[e] * (1.f / (float)NS_K));
    *(u16x8*)(lap + pt * 128 + c8) = o;
}

// ---------------------------------------------------------------------------
// Fold BN stats into per-channel scale/shift (1 block, 128 threads).
// ---------------------------------------------------------------------------
__global__ void bn_stats_kernel(const float* __restrict__ gsum,
                                const float* __restrict__ gsq,
                                const float* __restrict__ gamma,
                                const float* __restrict__ beta,
                                float* __restrict__ bnsc, float* __restrict__ bnsh)
{
    const int c = threadIdx.x;
    const float invN = 1.f / (float)N_PTS;
    const float mean = gsum[c] * invN;
    const float var  = gsq[c] * invN - mean * mean;
    const float sc   = rsqrtf(var + BN_EPS) * gamma[c];
    bnsc[c] = sc;
    bnsh[c] = fmaf(-mean, sc, beta[c]);
}

// ---------------------------------------------------------------------------
// BN apply + ReLU: 8 elems (one bf16x8 load, two float4 stores) per thread.
// ---------------------------------------------------------------------------
__global__ __launch_bounds__(256) void bn_relu_kernel(
    const ushort_t* __restrict__ h, const float* __restrict__ bnsc,
    const float* __restrict__ bnsh, float* __restrict__ out)
{
    const size_t i = (size_t)blockIdx.x * 256 + threadIdx.x;
    const int c8 = (threadIdx.x * 8) & 127;   // block covers 2048 elems = 16 full rows

    const u16x8 hv = *(const u16x8*)(h + i * 8);
    const f32x4 sc0 = *(const f32x4*)(bnsc + c8);
    const f32x4 sc1 = *(const f32x4*)(bnsc + c8 + 4);
    const f32x4 sh0 = *(const f32x4*)(bnsh + c8);
    const f32x4 sh1 = *(const f32x4*)(bnsh + c8 + 4);

    f32x4 o0, o1;
    #pragma unroll
    for (int e = 0; e < 4; e++) {
        o0[e] = fmaxf(fmaf(b2f(hv[e]),     sc0[e], sh0[e]), 0.f);
        o1[e] = fmaxf(fmaf(b2f(hv[4 + e]), sc1[e], sh1[e]), 0.f);
    }
    float* op = out + (size_t)3 * N_PTS + i * 8;
    *(f32x4*)(op)     = o0;
    *(f32x4*)(op + 4) = o1;
}

// ---------------------------------------------------------------------------
// Copy p (N*3 floats) and write o (as float value in f32 out buffer).
// ---------------------------------------------------------------------------
__global__ __launch_bounds__(256) void copy_p_kernel(
    const float* __restrict__ p, const int* __restrict__ o,
    float* __restrict__ out)
{
    const size_t i = (size_t)blockIdx.x * 256 + threadIdx.x;
    *(f32x4*)(out + i * 4) = *(const f32x4*)(p + i * 4);
    if (i == 0)
        out[(size_t)3 * N_PTS + (size_t)N_PTS * C_DIM] = (float)o[0];
}

extern "C" void kernel_launch(void* const* d_in, const int* in_sizes, int n_in,
                              void* d_out, int out_size, void* d_ws, size_t ws_size,
                              hipStream_t stream) {
    const float* p     = (const float*)d_in[0];
    const float* u     = (const float*)d_in[1];
    const int*   o     = (const int*)d_in[2];
    const int*   idx   = (const int*)d_in[3];
    const float* W1    = (const float*)d_in[4];
    const float* b1    = (const float*)d_in[5];
    const float* W2    = (const float*)d_in[6];
    const float* b2    = (const float*)d_in[7];
    const float* gamma = (const float*)d_in[8];
    const float* beta  = (const float*)d_in[9];
    float* out = (float*)d_out;

    char* ws = (char*)d_ws;
    const size_t buf_bytes = (size_t)N_PTS * C_DIM * sizeof(ushort_t);  // 32 MB
    ushort_t* table = (ushort_t*)ws;                       // u_pre, bf16
    ushort_t* lap   = (ushort_t*)(ws + buf_bytes);         // laplacian, bf16
    ushort_t* h     = (ushort_t*)(ws + 2 * buf_bytes);     // pre-BN, bf16
    float*    stats = (float*)(ws + 3 * buf_bytes);
    float* gsum = stats;        // [128]
    float* gsq  = stats + 128;  // [128]
    float* bnsc = stats + 256;  // [128]
    float* bnsh = stats + 384;  // [128]
    ushort_t* wT1 = (ushort_t*)(stats + 512);              // [128*128] bf16
    ushort_t* wT2 = wT1 + 128 * 128;

    hipMemsetAsync(stats, 0, 256 * sizeof(float), stream);

    prep_w_kernel<<<64, 256, 0, stream>>>(W1, W2, wT1, wT2);
    gemm_mfma_kernel<false, false><<<N_PTS / 128, 256, 0, stream>>>(
        u, wT1, b1, table, nullptr, nullptr);
    laplacian_kernel<<<N_PTS / 16, 256, 0, stream>>>(table, idx, lap);
    gemm_mfma_kernel<true, true><<<N_PTS / 128, 256, 0, stream>>>(
        lap, wT2, b2, h, gsum, gsq);
    bn_stats_kernel<<<1, 128, 0, stream>>>(gsum, gsq, gamma, beta, bnsc, bnsh);
    bn_relu_kernel<<<(N_PTS * C_DIM / 8) / 256, 256, 0, stream>>>(
        h, bnsc, bnsh, out);
    copy_p_kernel<<<(3 * N_PTS / 4) / 256, 256, 0, stream>>>(p, o, out);
}